// Round 6
// baseline (98.118 us; speedup 1.0000x reference)
//
#include <hip/hip_runtime.h>
#include <hip/hip_bf16.h>

// Problem constants: B=2, S=128, D=512, H=8, Dh=64. All I/O float32.
#define B_  2
#define S_  128
#define D_  512
#define H_  8
#define DH_ 64
#define IGNORE_VAL (-1.0e6f)
#define QB  2        // queries per tri block (interleaved: q = qg + 64*qq)  [R6: 4->2]

#define XSF 520      // ushort stride for full-K A tiles (1040 B rows, 16B-aligned)
#define K2S 72       // ushort stride for k2 LDS rows (conflict-free for b128, verified)

// log2(e)/64: folds BOTH the 1/64 score scale and the exp->exp2 conversion
// into the q pre-scale, so softmax exp is a single raw v_exp_f32.  [R6]
#define QSCALE 0.022542110f
#define MASKED_L2 (-22542.11f)   // IGNORE_VAL * QSCALE; exp2 -> 0

typedef __attribute__((ext_vector_type(8))) short bf16x8;   // MFMA A/B frag (4 VGPRs)
typedef __attribute__((ext_vector_type(4))) float f32x4;    // MFMA C/D frag
typedef __attribute__((ext_vector_type(2))) __bf16 bf16x2;  // build_vector -> v_cvt_pk_bf16_f32

// Hardware RNE conversion via native __bf16 cast; 2-element build_vector
// lowers to ONE v_cvt_pk_bf16_f32 (verified bit-identical to manual RNE, R5).
__device__ __forceinline__ unsigned short f2bf(float f) {
    __bf16 h = (__bf16)f;
    return __builtin_bit_cast(unsigned short, h);
}
__device__ __forceinline__ unsigned f2bf2(float lo, float hi) {
    bf16x2 h = { (__bf16)lo, (__bf16)hi };
    return __builtin_bit_cast(unsigned, h);
}

// ---------------- Kernel 1: fused projection GEMM (bf16 MFMA) ---------------
// A = x (256 x 512), virtual W = [W_kkq | Wv_a | Wv_b] (512 x 2560).
// Tile 32 rows x 64 cols, grid (40, 8) = 320 blocks. A staged in LDS once
// (32x512 bf16 = 33 KB, 1 barrier); W loaded direct global->reg (zero reuse
// within block). Each wave: 16-col slice x 2 m-tiles (acc[2]).
// cb: 0..7 k1 | 8..15 k2 | 16..23 q | 24..31 va | 32..39 vb (head n = cb&7).
__global__ __launch_bounds__(256) void proj_kernel(
    const float* __restrict__ x,
    const float* __restrict__ W_kkq, const float* __restrict__ b_kkq,
    const float* __restrict__ Wv_a,  const float* __restrict__ Wv_b,
    float* __restrict__ k1_ws, unsigned short* __restrict__ k2bf, float* __restrict__ q_ws,
    float* __restrict__ va_ws, float* __restrict__ vb_ws)
{
    __shared__ __align__(16) unsigned short xs[32 * XSF];   // 33280 B

    const int cb = blockIdx.x;           // 0..39
    const int rb = blockIdx.y;           // 0..7 (32 rows each)
    const int tid = threadIdx.x;
    const int lane = tid & 63, wvx = tid >> 6;
    const int n16 = lane & 15, quad = lane >> 4;

    const int part = cb >> 3;            // 0 k1, 1 k2, 2 q, 3 va, 4 vb
    const float* Wbase; int wstride; int wcoloff;
    if (part <= 2) { Wbase = W_kkq; wstride = 1536; wcoloff = cb * 64; }
    else if (part == 3) { Wbase = Wv_a; wstride = 512; wcoloff = (cb - 24) * 64; }
    else { Wbase = Wv_b; wstride = 512; wcoloff = (cb - 32) * 64; }

    // Stage full A tile: 32 rows x 512 k, f32 -> bf16 (cvt_pk). Wave-coalesced.
    {
        const int c = (tid & 63) * 8;
#pragma unroll
        for (int i = 0; i < 8; ++i) {
            const int m = (tid >> 6) + i * 4;
            const float* src = x + (size_t)(rb * 32 + m) * D_ + c;
            const float4 a = *reinterpret_cast<const float4*>(src);
            const float4 b4 = *reinterpret_cast<const float4*>(src + 4);
            uint4 pk;
            pk.x = f2bf2(a.x,  a.y);
            pk.y = f2bf2(a.z,  a.w);
            pk.z = f2bf2(b4.x, b4.y);
            pk.w = f2bf2(b4.z, b4.w);
            *reinterpret_cast<uint4*>(&xs[m * XSF + c]) = pk;
        }
    }
    __syncthreads();   // the ONLY barrier in this kernel

    f32x4 acc[2];
    acc[0] = (f32x4){0.f, 0.f, 0.f, 0.f};
    acc[1] = (f32x4){0.f, 0.f, 0.f, 0.f};
    const int ncol = wcoloff + wvx * 16 + n16;   // this lane's W column

#pragma unroll
    for (int ks = 0; ks < 8; ++ks) {
#pragma unroll
        for (int kk = 0; kk < 2; ++kk) {
            const int k = ks * 64 + kk * 32 + quad * 8;
            // B-frag direct from global: 8 consecutive-k f32 at fixed col
            const float* wp = Wbase + (size_t)k * wstride + ncol;
            float w[8];
#pragma unroll
            for (int j = 0; j < 8; ++j) w[j] = wp[(size_t)j * wstride];
            bf16x8 bf;
            unsigned* bu = reinterpret_cast<unsigned*>(&bf);
            bu[0] = f2bf2(w[0], w[1]);
            bu[1] = f2bf2(w[2], w[3]);
            bu[2] = f2bf2(w[4], w[5]);
            bu[3] = f2bf2(w[6], w[7]);
            const bf16x8 af0 = *reinterpret_cast<const bf16x8*>(&xs[n16 * XSF + k]);
            const bf16x8 af1 = *reinterpret_cast<const bf16x8*>(&xs[(16 + n16) * XSF + k]);
            acc[0] = __builtin_amdgcn_mfma_f32_16x16x32_bf16(af0, bf, acc[0], 0, 0, 0);
            acc[1] = __builtin_amdgcn_mfma_f32_16x16x32_bf16(af1, bf, acc[1], 0, 0, 0);
        }
    }

    // epilogue: C row = mt*16 + quad*4 + r, col = wvx*16 + n16 (m89 layout)
    const int n_head = cb & 7;
    const int h = wvx * 16 + n16;
    const float bias = (part <= 2) ? b_kkq[cb * 64 + h] : 0.f;
    float* Obase = (part == 0) ? k1_ws : (part == 2) ? q_ws
                 : (part == 3) ? va_ws : vb_ws;
#pragma unroll
    for (int mt = 0; mt < 2; ++mt) {
#pragma unroll
        for (int r = 0; r < 4; ++r) {
            const int row = rb * 32 + mt * 16 + quad * 4 + r;   // b*128 + s
            const int b = row >> 7, s = row & 127;
            const size_t o = (((size_t)(b * H_ + n_head) * S_ + s) << 6) + h;
            const float val = acc[mt][r] + bias;
            if (part == 1) k2bf[o] = f2bf(val);
            else           Obase[o] = val;
        }
    }
}

// ---------------- Kernel 2: MFMA tri-scores + softmax marginals + z ---------
// R6: QB=2, grid (64, 8, 2) = 1024 blocks (4 blocks/CU, 16 waves/CU) -- double
// the occupancy, half the per-block serial qq chain (tri was latency-bound at
// 2 blocks/CU). Plus exp2 fold: qv pre-scaled by log2(e)/64 so softmax exp is
// a single raw v_exp_f32 (removes the v_mul-by-log2e __expf emits).
__global__ __launch_bounds__(256) void tri_kernel(
    const float* __restrict__ k1_ws, const unsigned short* __restrict__ k2bf,
    const float* __restrict__ q_ws,
    const float* __restrict__ va_ws, const float* __restrict__ vb_ws,
    const float* __restrict__ b_v,
    unsigned short* __restrict__ z_bf)
{
    const int qg = blockIdx.x;           // 0..63
    const int n = blockIdx.y;
    const int b = blockIdx.z;
    const int head = b * H_ + n;
    const float* k1h = k1_ws + (size_t)head * S_ * DH_;
    const unsigned short* k2hb = k2bf + (size_t)head * S_ * DH_;
    const float* qh = q_ws + (size_t)head * S_ * DH_;
    const float* va_h = va_ws + (size_t)head * S_ * DH_;
    const float* vb_h = vb_ws + (size_t)head * S_ * DH_;

    __shared__ __align__(16) unsigned short k2s[S_ * K2S];   // 18432 B
    __shared__ __align__(16) float qv[QB][DH_];
    __shared__ float Asm[QB][S_];
    __shared__ float Atm[QB][S_];
    __shared__ float Atp[QB][4][S_];
    __shared__ float reds[QB][4];
    __shared__ float zred[4][QB][DH_];

    const int tid = threadIdx.x;
    const int lane = tid & 63, wv = tid >> 6;
    const int row16 = lane & 15, quad = lane >> 4;

    if (tid < QB * DH_)   // q pre-scaled by log2(e)/64 (R6 exp2 fold)
        qv[tid >> 6][tid & 63] =
            qh[(size_t)(qg + 64 * (tid >> 6)) * DH_ + (tid & 63)] * QSCALE;
#pragma unroll
    for (int it = 0; it < 4; ++it) {
        const int i8 = (tid + it * 256) * 8;
        const int r = i8 >> 6, c = i8 & 63;
        uint4 v = *reinterpret_cast<const uint4*>(k2hb + i8);
        *reinterpret_cast<uint4*>(&k2s[r * K2S + c]) = v;
    }

    // k1 f32 fragments, kept across the q-loop. A[m=lane&15][k=quad*8+j]
    float k1f[2][2][8];
#pragma unroll
    for (int mt = 0; mt < 2; ++mt) {
        const int srow = (wv * 2 + mt) * 16 + row16;
#pragma unroll
        for (int kk = 0; kk < 2; ++kk) {
            const int k = kk * 32 + quad * 8;
            const float4 u0 = *reinterpret_cast<const float4*>(k1h + (size_t)srow * DH_ + k);
            const float4 u1 = *reinterpret_cast<const float4*>(k1h + (size_t)srow * DH_ + k + 4);
            k1f[mt][kk][0] = u0.x; k1f[mt][kk][1] = u0.y; k1f[mt][kk][2] = u0.z; k1f[mt][kk][3] = u0.w;
            k1f[mt][kk][4] = u1.x; k1f[mt][kk][5] = u1.y; k1f[mt][kk][6] = u1.z; k1f[mt][kk][7] = u1.w;
        }
    }
    __syncthreads();

    for (int qq = 0; qq < QB; ++qq) {
        const int qidx = qg + 64 * qq;
        const int ntlim = qidx >> 4;        // tiles nt > ntlim fully masked (exp = 0)

        bf16x8 afrag[2][2];
#pragma unroll
        for (int mt = 0; mt < 2; ++mt)
#pragma unroll
            for (int kk = 0; kk < 2; ++kk) {
                const int k = kk * 32 + quad * 8;
                bf16x8 f;
                unsigned* fu = reinterpret_cast<unsigned*>(&f);
                fu[0] = f2bf2(k1f[mt][kk][0] * qv[qq][k + 0], k1f[mt][kk][1] * qv[qq][k + 1]);
                fu[1] = f2bf2(k1f[mt][kk][2] * qv[qq][k + 2], k1f[mt][kk][3] * qv[qq][k + 3]);
                fu[2] = f2bf2(k1f[mt][kk][4] * qv[qq][k + 4], k1f[mt][kk][5] * qv[qq][k + 5]);
                fu[3] = f2bf2(k1f[mt][kk][6] * qv[qq][k + 6], k1f[mt][kk][7] * qv[qq][k + 7]);
                afrag[mt][kk] = f;
            }

        f32x4 acc[2][8];
#pragma unroll
        for (int mt = 0; mt < 2; ++mt)
#pragma unroll
            for (int nt = 0; nt < 8; ++nt) acc[mt][nt] = (f32x4){0.f, 0.f, 0.f, 0.f};
#pragma unroll
        for (int nt = 0; nt < 8; ++nt) {
            if (nt <= ntlim) {              // wave-uniform guard, indices compile-time
#pragma unroll
                for (int kk = 0; kk < 2; ++kk) {
                    bf16x8 bfrag = *reinterpret_cast<const bf16x8*>(
                        &k2s[(nt * 16 + row16) * K2S + kk * 32 + quad * 8]);
                    acc[0][nt] = __builtin_amdgcn_mfma_f32_16x16x32_bf16(afrag[0][kk], bfrag, acc[0][nt], 0, 0, 0);
                    acc[1][nt] = __builtin_amdgcn_mfma_f32_16x16x32_bf16(afrag[1][kk], bfrag, acc[1][nt], 0, 0, 0);
                }
            }
        }

        float rs[2][4], cs[8];
#pragma unroll
        for (int nt = 0; nt < 8; ++nt) cs[nt] = 0.f;
#pragma unroll
        for (int mt = 0; mt < 2; ++mt)
#pragma unroll
            for (int r = 0; r < 4; ++r) rs[mt][r] = 0.f;
#pragma unroll
        for (int nt = 0; nt < 8; ++nt) {
            if (nt <= ntlim) {
                const int t = nt * 16 + row16;
                const bool msk = (t > qidx);
#pragma unroll
                for (int mt = 0; mt < 2; ++mt)
#pragma unroll
                    for (int r = 0; r < 4; ++r) {
                        // scores arrive pre-scaled by log2(e)/64 -> raw exp2
                        float v = msk ? MASKED_L2 : acc[mt][nt][r];
                        float p = __builtin_amdgcn_exp2f(v);
                        rs[mt][r] += p;
                        cs[nt] += p;
                    }
            }
        }

        // row sums across lane bits 0..3
#pragma unroll
        for (int m = 1; m < 16; m <<= 1)
#pragma unroll
            for (int mt = 0; mt < 2; ++mt)
#pragma unroll
                for (int r = 0; r < 4; ++r) rs[mt][r] += __shfl_xor(rs[mt][r], m, 64);
        if (row16 == 0) {
#pragma unroll
            for (int mt = 0; mt < 2; ++mt)
#pragma unroll
                for (int r = 0; r < 4; ++r)
                    Asm[qq][(wv * 2 + mt) * 16 + quad * 4 + r] = rs[mt][r];
        }

        // col sums across lane bits 4..5 -> per-wave partials (guarded, unrolled)
#pragma unroll
        for (int nt = 0; nt < 8; ++nt) {
            if (nt <= ntlim) {
#pragma unroll
                for (int m = 16; m < 64; m <<= 1) cs[nt] += __shfl_xor(cs[nt], m, 64);
            }
        }
        if (quad == 0) {
#pragma unroll
            for (int nt = 0; nt < 8; ++nt) Atp[qq][wv][nt * 16 + row16] = cs[nt];
        }

        float tot = rs[0][0] + rs[0][1] + rs[0][2] + rs[0][3]
                  + rs[1][0] + rs[1][1] + rs[1][2] + rs[1][3];
#pragma unroll
        for (int m = 16; m < 64; m <<= 1) tot += __shfl_xor(tot, m, 64);
        if (lane == 0) reds[qq][wv] = tot;
    }
    __syncthreads();

    for (int i = tid; i < QB * S_; i += 256) {
        const int qq = i >> 7, t = i & 127;
        Atm[qq][t] = Atp[qq][0][t] + Atp[qq][1][t] + Atp[qq][2][t] + Atp[qq][3][t];
    }
    __syncthreads();

    // epilogue, s-major: read va/vb rows once, FMA into QB q-accumulators
    {
        const int h = tid & 63, w = tid >> 6;
        float za[QB] = {0.f, 0.f};
        for (int i = 0; i < 32; ++i) {
            const int s = w * 32 + i;
            const float va_v = va_h[(size_t)s * DH_ + h];
            const float vb_v = vb_h[(size_t)s * DH_ + h];
#pragma unroll
            for (int qq = 0; qq < QB; ++qq)
                za[qq] += Asm[qq][s] * va_v + Atm[qq][s] * vb_v;
        }
#pragma unroll
        for (int qq = 0; qq < QB; ++qq) zred[w][qq][h] = za[qq];
    }
    __syncthreads();

    if (tid < QB * 64) {
        const int qq = tid >> 6, h = tid & 63;
        const float Zv = reds[qq][0] + reds[qq][1] + reds[qq][2] + reds[qq][3];
        float zv = zred[0][qq][h] + zred[1][qq][h] + zred[2][qq][h] + zred[3][qq][h];
        zv = zv / Zv + b_v[n * DH_ + h];
        z_bf[((size_t)(b * S_ + qg + 64 * qq) * (H_ * DH_)) + n * DH_ + h] = f2bf(zv);
    }
}

// ---------------- Kernel 3: out = z @ W_out + b_out (bf16 MFMA) -------------
// z tile (16x512 bf16, already bf16 -> raw copy) staged once, W_out direct
// global->reg (cvt_pk). One barrier per block.
__global__ __launch_bounds__(256) void out_kernel(
    const unsigned short* __restrict__ z_bf,
    const float* __restrict__ W_out, const float* __restrict__ b_out,
    float* __restrict__ out)
{
    __shared__ __align__(16) unsigned short zs[16 * XSF];   // 16640 B

    const int cb = blockIdx.x;           // 0..7 (64 cols)
    const int rb = blockIdx.y;           // 0..15 (16 rows)
    const int tid = threadIdx.x;
    const int lane = tid & 63, wvx = tid >> 6;
    const int n16 = lane & 15, quad = lane >> 4;

    // Stage full z tile: 16 rows x 512 k bf16 (raw uint4 copy, 2 KB/instr)
    {
        const int c = (tid & 63) * 8;
#pragma unroll
        for (int i = 0; i < 4; ++i) {
            const int m = (tid >> 6) + i * 4;
            uint4 v = *reinterpret_cast<const uint4*>(
                z_bf + (size_t)(rb * 16 + m) * 512 + c);
            *reinterpret_cast<uint4*>(&zs[m * XSF + c]) = v;
        }
    }
    __syncthreads();   // the ONLY barrier

    f32x4 acc = (f32x4){0.f, 0.f, 0.f, 0.f};
    const int ncol = cb * 64 + wvx * 16 + n16;

#pragma unroll
    for (int ks = 0; ks < 8; ++ks) {
#pragma unroll
        for (int kk = 0; kk < 2; ++kk) {
            const int k = ks * 64 + kk * 32 + quad * 8;
            const float* wp = W_out + (size_t)k * 512 + ncol;
            float w[8];
#pragma unroll
            for (int j = 0; j < 8; ++j) w[j] = wp[(size_t)j * 512];
            bf16x8 bf;
            unsigned* bu = reinterpret_cast<unsigned*>(&bf);
            bu[0] = f2bf2(w[0], w[1]);
            bu[1] = f2bf2(w[2], w[3]);
            bu[2] = f2bf2(w[4], w[5]);
            bu[3] = f2bf2(w[6], w[7]);
            const bf16x8 af = *reinterpret_cast<const bf16x8*>(&zs[n16 * XSF + k]);
            acc = __builtin_amdgcn_mfma_f32_16x16x32_bf16(af, bf, acc, 0, 0, 0);
        }
    }

    const float bias = b_out[ncol];
#pragma unroll
    for (int r = 0; r < 4; ++r) {
        const int row = rb * 16 + quad * 4 + r;
        out[(size_t)row * 512 + ncol] = acc[r] + bias;
    }
}

// ---------------------------------------------------------------------------
extern "C" void kernel_launch(void* const* d_in, const int* in_sizes, int n_in,
                              void* d_out, int out_size, void* d_ws, size_t ws_size,
                              hipStream_t stream) {
    const float* x     = (const float*)d_in[0];
    const float* W_kkq = (const float*)d_in[1];
    const float* b_kkq = (const float*)d_in[2];
    const float* Wv_a  = (const float*)d_in[3];
    const float* Wv_b  = (const float*)d_in[4];
    const float* b_v   = (const float*)d_in[5];
    const float* W_out = (const float*)d_in[6];
    const float* b_out = (const float*)d_in[7];
    float* out = (float*)d_out;

    const size_t HE = (size_t)B_ * H_ * S_ * DH_;   // 131072
    float* ws = (float*)d_ws;
    float* k1_ws = ws;
    float* q_ws  = ws + HE;
    float* va_ws = ws + 2 * HE;
    float* vb_ws = ws + 3 * HE;
    unsigned short* k2bf = (unsigned short*)(ws + 4 * HE);          // HE ushorts
    unsigned short* z_bf = (unsigned short*)(ws + 4 * HE) + HE;     // HE ushorts

    proj_kernel<<<dim3(40, 8), 256, 0, stream>>>(x, W_kkq, b_kkq, Wv_a, Wv_b,
                                                 k1_ws, k2bf, q_ws, va_ws, vb_ws);
    tri_kernel<<<dim3(64, H_, B_), 256, 0, stream>>>(k1_ws, k2bf, q_ws,
                                                     va_ws, vb_ws, b_v, z_bf);
    out_kernel<<<dim3(8, 16), 256, 0, stream>>>(z_bf, W_out, b_out, out);
}

// Round 7
// 97.057 us; speedup vs baseline: 1.0109x; 1.0109x over previous
//
#include <hip/hip_runtime.h>
#include <hip/hip_bf16.h>

// Problem constants: B=2, S=128, D=512, H=8, Dh=64. All I/O float32.
#define B_  2
#define S_  128
#define D_  512
#define H_  8
#define DH_ 64
#define IGNORE_VAL (-1.0e6f)
#define QB  4        // queries per tri block (interleaved: q = qg + 32*qq)  [R7: back to 4]

#define XSF 520      // ushort stride for full-K A tiles (1040 B rows, 16B-aligned)
#define K2S 72       // ushort stride for k2 LDS rows (conflict-free for b128, verified)

// log2(e)/64: folds BOTH the 1/64 score scale and the exp->exp2 conversion
// into the q pre-scale, so softmax exp is a single raw v_exp_f32.
#define QSCALE 0.022542110f
#define MASKED_L2 (-22542.11f)   // IGNORE_VAL * QSCALE; exp2 -> 0

typedef __attribute__((ext_vector_type(8))) short bf16x8;   // MFMA A/B frag (4 VGPRs)
typedef __attribute__((ext_vector_type(4))) float f32x4;    // MFMA C/D frag
typedef __attribute__((ext_vector_type(2))) __bf16 bf16x2;  // build_vector -> v_cvt_pk_bf16_f32

// Hardware RNE conversion via native __bf16 cast; 2-element build_vector
// lowers to ONE v_cvt_pk_bf16_f32 (verified bit-identical to manual RNE, R5).
__device__ __forceinline__ unsigned short f2bf(float f) {
    __bf16 h = (__bf16)f;
    return __builtin_bit_cast(unsigned short, h);
}
__device__ __forceinline__ unsigned f2bf2(float lo, float hi) {
    bf16x2 h = { (__bf16)lo, (__bf16)hi };
    return __builtin_bit_cast(unsigned, h);
}

// ---------------- Kernel 1: fused projection GEMM (bf16 MFMA) ---------------
// A = x (256 x 512), virtual W = [W_kkq | Wv_a | Wv_b] (512 x 2560).
// Tile 32 rows x 64 cols, grid (40, 8) = 320 blocks. A staged in LDS once
// (32x512 bf16 = 33 KB, 1 barrier); W loaded direct global->reg (zero reuse
// within block). Each wave: 16-col slice x 2 m-tiles (acc[2]).
// cb: 0..7 k1 | 8..15 k2 | 16..23 q | 24..31 va | 32..39 vb (head n = cb&7).
__global__ __launch_bounds__(256) void proj_kernel(
    const float* __restrict__ x,
    const float* __restrict__ W_kkq, const float* __restrict__ b_kkq,
    const float* __restrict__ Wv_a,  const float* __restrict__ Wv_b,
    float* __restrict__ k1_ws, unsigned short* __restrict__ k2bf, float* __restrict__ q_ws,
    float* __restrict__ va_ws, float* __restrict__ vb_ws)
{
    __shared__ __align__(16) unsigned short xs[32 * XSF];   // 33280 B

    const int cb = blockIdx.x;           // 0..39
    const int rb = blockIdx.y;           // 0..7 (32 rows each)
    const int tid = threadIdx.x;
    const int lane = tid & 63, wvx = tid >> 6;
    const int n16 = lane & 15, quad = lane >> 4;

    const int part = cb >> 3;            // 0 k1, 1 k2, 2 q, 3 va, 4 vb
    const float* Wbase; int wstride; int wcoloff;
    if (part <= 2) { Wbase = W_kkq; wstride = 1536; wcoloff = cb * 64; }
    else if (part == 3) { Wbase = Wv_a; wstride = 512; wcoloff = (cb - 24) * 64; }
    else { Wbase = Wv_b; wstride = 512; wcoloff = (cb - 32) * 64; }

    // Stage full A tile: 32 rows x 512 k, f32 -> bf16 (cvt_pk). Wave-coalesced.
    {
        const int c = (tid & 63) * 8;
#pragma unroll
        for (int i = 0; i < 8; ++i) {
            const int m = (tid >> 6) + i * 4;
            const float* src = x + (size_t)(rb * 32 + m) * D_ + c;
            const float4 a = *reinterpret_cast<const float4*>(src);
            const float4 b4 = *reinterpret_cast<const float4*>(src + 4);
            uint4 pk;
            pk.x = f2bf2(a.x,  a.y);
            pk.y = f2bf2(a.z,  a.w);
            pk.z = f2bf2(b4.x, b4.y);
            pk.w = f2bf2(b4.z, b4.w);
            *reinterpret_cast<uint4*>(&xs[m * XSF + c]) = pk;
        }
    }
    __syncthreads();   // the ONLY barrier in this kernel

    f32x4 acc[2];
    acc[0] = (f32x4){0.f, 0.f, 0.f, 0.f};
    acc[1] = (f32x4){0.f, 0.f, 0.f, 0.f};
    const int ncol = wcoloff + wvx * 16 + n16;   // this lane's W column

#pragma unroll
    for (int ks = 0; ks < 8; ++ks) {
#pragma unroll
        for (int kk = 0; kk < 2; ++kk) {
            const int k = ks * 64 + kk * 32 + quad * 8;
            // B-frag direct from global: 8 consecutive-k f32 at fixed col
            const float* wp = Wbase + (size_t)k * wstride + ncol;
            float w[8];
#pragma unroll
            for (int j = 0; j < 8; ++j) w[j] = wp[(size_t)j * wstride];
            bf16x8 bf;
            unsigned* bu = reinterpret_cast<unsigned*>(&bf);
            bu[0] = f2bf2(w[0], w[1]);
            bu[1] = f2bf2(w[2], w[3]);
            bu[2] = f2bf2(w[4], w[5]);
            bu[3] = f2bf2(w[6], w[7]);
            const bf16x8 af0 = *reinterpret_cast<const bf16x8*>(&xs[n16 * XSF + k]);
            const bf16x8 af1 = *reinterpret_cast<const bf16x8*>(&xs[(16 + n16) * XSF + k]);
            acc[0] = __builtin_amdgcn_mfma_f32_16x16x32_bf16(af0, bf, acc[0], 0, 0, 0);
            acc[1] = __builtin_amdgcn_mfma_f32_16x16x32_bf16(af1, bf, acc[1], 0, 0, 0);
        }
    }

    // epilogue: C row = mt*16 + quad*4 + r, col = wvx*16 + n16 (m89 layout)
    const int n_head = cb & 7;
    const int h = wvx * 16 + n16;
    const float bias = (part <= 2) ? b_kkq[cb * 64 + h] : 0.f;
    float* Obase = (part == 0) ? k1_ws : (part == 2) ? q_ws
                 : (part == 3) ? va_ws : vb_ws;
#pragma unroll
    for (int mt = 0; mt < 2; ++mt) {
#pragma unroll
        for (int r = 0; r < 4; ++r) {
            const int row = rb * 32 + mt * 16 + quad * 4 + r;   // b*128 + s
            const int b = row >> 7, s = row & 127;
            const size_t o = (((size_t)(b * H_ + n_head) * S_ + s) << 6) + h;
            const float val = acc[mt][r] + bias;
            if (part == 1) k2bf[o] = f2bf(val);
            else           Obase[o] = val;
        }
    }
}

// ---------------- Kernel 2: MFMA tri-scores + softmax marginals + z ---------
// R7: QB=4 structure restored (R6's QB=2 split doubled chip-wide k2-staging
// cost and regressed); exp2 fold KEPT: qv pre-scaled by log2(e)/64 so the
// softmax exp is a single raw v_exp_f32 per element.
__global__ __launch_bounds__(256) void tri_kernel(
    const float* __restrict__ k1_ws, const unsigned short* __restrict__ k2bf,
    const float* __restrict__ q_ws,
    const float* __restrict__ va_ws, const float* __restrict__ vb_ws,
    const float* __restrict__ b_v,
    unsigned short* __restrict__ z_bf)
{
    const int qg = blockIdx.x;           // 0..31
    const int n = blockIdx.y;
    const int b = blockIdx.z;
    const int head = b * H_ + n;
    const float* k1h = k1_ws + (size_t)head * S_ * DH_;
    const unsigned short* k2hb = k2bf + (size_t)head * S_ * DH_;
    const float* qh = q_ws + (size_t)head * S_ * DH_;
    const float* va_h = va_ws + (size_t)head * S_ * DH_;
    const float* vb_h = vb_ws + (size_t)head * S_ * DH_;

    __shared__ __align__(16) unsigned short k2s[S_ * K2S];   // 18432 B
    __shared__ __align__(16) float qv[QB][DH_];
    __shared__ float Asm[QB][S_];
    __shared__ float Atm[QB][S_];
    __shared__ float Atp[QB][4][S_];
    __shared__ float reds[QB][4];
    __shared__ float zred[4][QB][DH_];

    const int tid = threadIdx.x;
    const int lane = tid & 63, wv = tid >> 6;
    const int row16 = lane & 15, quad = lane >> 4;

    if (tid < QB * DH_)   // q pre-scaled by log2(e)/64 (exp2 fold)
        qv[tid >> 6][tid & 63] =
            qh[(size_t)(qg + 32 * (tid >> 6)) * DH_ + (tid & 63)] * QSCALE;
#pragma unroll
    for (int it = 0; it < 4; ++it) {
        const int i8 = (tid + it * 256) * 8;
        const int r = i8 >> 6, c = i8 & 63;
        uint4 v = *reinterpret_cast<const uint4*>(k2hb + i8);
        *reinterpret_cast<uint4*>(&k2s[r * K2S + c]) = v;
    }

    // k1 f32 fragments, kept across the q-loop. A[m=lane&15][k=quad*8+j]
    float k1f[2][2][8];
#pragma unroll
    for (int mt = 0; mt < 2; ++mt) {
        const int srow = (wv * 2 + mt) * 16 + row16;
#pragma unroll
        for (int kk = 0; kk < 2; ++kk) {
            const int k = kk * 32 + quad * 8;
            const float4 u0 = *reinterpret_cast<const float4*>(k1h + (size_t)srow * DH_ + k);
            const float4 u1 = *reinterpret_cast<const float4*>(k1h + (size_t)srow * DH_ + k + 4);
            k1f[mt][kk][0] = u0.x; k1f[mt][kk][1] = u0.y; k1f[mt][kk][2] = u0.z; k1f[mt][kk][3] = u0.w;
            k1f[mt][kk][4] = u1.x; k1f[mt][kk][5] = u1.y; k1f[mt][kk][6] = u1.z; k1f[mt][kk][7] = u1.w;
        }
    }
    __syncthreads();

    for (int qq = 0; qq < QB; ++qq) {
        const int qidx = qg + 32 * qq;
        const int ntlim = qidx >> 4;        // tiles nt > ntlim fully masked (exp = 0)

        bf16x8 afrag[2][2];
#pragma unroll
        for (int mt = 0; mt < 2; ++mt)
#pragma unroll
            for (int kk = 0; kk < 2; ++kk) {
                const int k = kk * 32 + quad * 8;
                bf16x8 f;
                unsigned* fu = reinterpret_cast<unsigned*>(&f);
                fu[0] = f2bf2(k1f[mt][kk][0] * qv[qq][k + 0], k1f[mt][kk][1] * qv[qq][k + 1]);
                fu[1] = f2bf2(k1f[mt][kk][2] * qv[qq][k + 2], k1f[mt][kk][3] * qv[qq][k + 3]);
                fu[2] = f2bf2(k1f[mt][kk][4] * qv[qq][k + 4], k1f[mt][kk][5] * qv[qq][k + 5]);
                fu[3] = f2bf2(k1f[mt][kk][6] * qv[qq][k + 6], k1f[mt][kk][7] * qv[qq][k + 7]);
                afrag[mt][kk] = f;
            }

        f32x4 acc[2][8];
#pragma unroll
        for (int mt = 0; mt < 2; ++mt)
#pragma unroll
            for (int nt = 0; nt < 8; ++nt) acc[mt][nt] = (f32x4){0.f, 0.f, 0.f, 0.f};
#pragma unroll
        for (int nt = 0; nt < 8; ++nt) {
            if (nt <= ntlim) {              // wave-uniform guard, indices compile-time
#pragma unroll
                for (int kk = 0; kk < 2; ++kk) {
                    bf16x8 bfrag = *reinterpret_cast<const bf16x8*>(
                        &k2s[(nt * 16 + row16) * K2S + kk * 32 + quad * 8]);
                    acc[0][nt] = __builtin_amdgcn_mfma_f32_16x16x32_bf16(afrag[0][kk], bfrag, acc[0][nt], 0, 0, 0);
                    acc[1][nt] = __builtin_amdgcn_mfma_f32_16x16x32_bf16(afrag[1][kk], bfrag, acc[1][nt], 0, 0, 0);
                }
            }
        }

        float rs[2][4], cs[8];
#pragma unroll
        for (int nt = 0; nt < 8; ++nt) cs[nt] = 0.f;
#pragma unroll
        for (int mt = 0; mt < 2; ++mt)
#pragma unroll
            for (int r = 0; r < 4; ++r) rs[mt][r] = 0.f;
#pragma unroll
        for (int nt = 0; nt < 8; ++nt) {
            if (nt <= ntlim) {
                const int t = nt * 16 + row16;
                const bool msk = (t > qidx);
#pragma unroll
                for (int mt = 0; mt < 2; ++mt)
#pragma unroll
                    for (int r = 0; r < 4; ++r) {
                        // scores arrive pre-scaled by log2(e)/64 -> raw exp2
                        float v = msk ? MASKED_L2 : acc[mt][nt][r];
                        float p = __builtin_amdgcn_exp2f(v);
                        rs[mt][r] += p;
                        cs[nt] += p;
                    }
            }
        }

        // row sums across lane bits 0..3
#pragma unroll
        for (int m = 1; m < 16; m <<= 1)
#pragma unroll
            for (int mt = 0; mt < 2; ++mt)
#pragma unroll
                for (int r = 0; r < 4; ++r) rs[mt][r] += __shfl_xor(rs[mt][r], m, 64);
        if (row16 == 0) {
#pragma unroll
            for (int mt = 0; mt < 2; ++mt)
#pragma unroll
                for (int r = 0; r < 4; ++r)
                    Asm[qq][(wv * 2 + mt) * 16 + quad * 4 + r] = rs[mt][r];
        }

        // col sums across lane bits 4..5 -> per-wave partials (guarded, unrolled)
#pragma unroll
        for (int nt = 0; nt < 8; ++nt) {
            if (nt <= ntlim) {
#pragma unroll
                for (int m = 16; m < 64; m <<= 1) cs[nt] += __shfl_xor(cs[nt], m, 64);
            }
        }
        if (quad == 0) {
#pragma unroll
            for (int nt = 0; nt < 8; ++nt) Atp[qq][wv][nt * 16 + row16] = cs[nt];
        }

        float tot = rs[0][0] + rs[0][1] + rs[0][2] + rs[0][3]
                  + rs[1][0] + rs[1][1] + rs[1][2] + rs[1][3];
#pragma unroll
        for (int m = 16; m < 64; m <<= 1) tot += __shfl_xor(tot, m, 64);
        if (lane == 0) reds[qq][wv] = tot;
    }
    __syncthreads();

    for (int i = tid; i < QB * S_; i += 256) {
        const int qq = i >> 7, t = i & 127;
        Atm[qq][t] = Atp[qq][0][t] + Atp[qq][1][t] + Atp[qq][2][t] + Atp[qq][3][t];
    }
    __syncthreads();

    // epilogue, s-major: read va/vb rows once, FMA into 4 q-accumulators
    {
        const int h = tid & 63, w = tid >> 6;
        float za[QB] = {0.f, 0.f, 0.f, 0.f};
        for (int i = 0; i < 32; ++i) {
            const int s = w * 32 + i;
            const float va_v = va_h[(size_t)s * DH_ + h];
            const float vb_v = vb_h[(size_t)s * DH_ + h];
#pragma unroll
            for (int qq = 0; qq < QB; ++qq)
                za[qq] += Asm[qq][s] * va_v + Atm[qq][s] * vb_v;
        }
#pragma unroll
        for (int qq = 0; qq < QB; ++qq) zred[w][qq][h] = za[qq];
    }
    __syncthreads();

    {
        const int qq = tid >> 6, h = tid & 63;
        const float Zv = reds[qq][0] + reds[qq][1] + reds[qq][2] + reds[qq][3];
        float zv = zred[0][qq][h] + zred[1][qq][h] + zred[2][qq][h] + zred[3][qq][h];
        zv = zv / Zv + b_v[n * DH_ + h];
        z_bf[((size_t)(b * S_ + qg + 32 * qq) * (H_ * DH_)) + n * DH_ + h] = f2bf(zv);
    }
}

// ---------------- Kernel 3: out = z @ W_out + b_out (bf16 MFMA) -------------
// z tile (16x512 bf16, already bf16 -> raw copy) staged once, W_out direct
// global->reg (cvt_pk). One barrier per block.
__global__ __launch_bounds__(256) void out_kernel(
    const unsigned short* __restrict__ z_bf,
    const float* __restrict__ W_out, const float* __restrict__ b_out,
    float* __restrict__ out)
{
    __shared__ __align__(16) unsigned short zs[16 * XSF];   // 16640 B

    const int cb = blockIdx.x;           // 0..7 (64 cols)
    const int rb = blockIdx.y;           // 0..15 (16 rows)
    const int tid = threadIdx.x;
    const int lane = tid & 63, wvx = tid >> 6;
    const int n16 = lane & 15, quad = lane >> 4;

    // Stage full z tile: 16 rows x 512 k bf16 (raw uint4 copy, 2 KB/instr)
    {
        const int c = (tid & 63) * 8;
#pragma unroll
        for (int i = 0; i < 4; ++i) {
            const int m = (tid >> 6) + i * 4;
            uint4 v = *reinterpret_cast<const uint4*>(
                z_bf + (size_t)(rb * 16 + m) * 512 + c);
            *reinterpret_cast<uint4*>(&zs[m * XSF + c]) = v;
        }
    }
    __syncthreads();   // the ONLY barrier

    f32x4 acc = (f32x4){0.f, 0.f, 0.f, 0.f};
    const int ncol = cb * 64 + wvx * 16 + n16;

#pragma unroll
    for (int ks = 0; ks < 8; ++ks) {
#pragma unroll
        for (int kk = 0; kk < 2; ++kk) {
            const int k = ks * 64 + kk * 32 + quad * 8;
            const float* wp = W_out + (size_t)k * 512 + ncol;
            float w[8];
#pragma unroll
            for (int j = 0; j < 8; ++j) w[j] = wp[(size_t)j * 512];
            bf16x8 bf;
            unsigned* bu = reinterpret_cast<unsigned*>(&bf);
            bu[0] = f2bf2(w[0], w[1]);
            bu[1] = f2bf2(w[2], w[3]);
            bu[2] = f2bf2(w[4], w[5]);
            bu[3] = f2bf2(w[6], w[7]);
            const bf16x8 af = *reinterpret_cast<const bf16x8*>(&zs[n16 * XSF + k]);
            acc = __builtin_amdgcn_mfma_f32_16x16x32_bf16(af, bf, acc, 0, 0, 0);
        }
    }

    const float bias = b_out[ncol];
#pragma unroll
    for (int r = 0; r < 4; ++r) {
        const int row = rb * 16 + quad * 4 + r;
        out[(size_t)row * 512 + ncol] = acc[r] + bias;
    }
}

// ---------------------------------------------------------------------------
extern "C" void kernel_launch(void* const* d_in, const int* in_sizes, int n_in,
                              void* d_out, int out_size, void* d_ws, size_t ws_size,
                              hipStream_t stream) {
    const float* x     = (const float*)d_in[0];
    const float* W_kkq = (const float*)d_in[1];
    const float* b_kkq = (const float*)d_in[2];
    const float* Wv_a  = (const float*)d_in[3];
    const float* Wv_b  = (const float*)d_in[4];
    const float* b_v   = (const float*)d_in[5];
    const float* W_out = (const float*)d_in[6];
    const float* b_out = (const float*)d_in[7];
    float* out = (float*)d_out;

    const size_t HE = (size_t)B_ * H_ * S_ * DH_;   // 131072
    float* ws = (float*)d_ws;
    float* k1_ws = ws;
    float* q_ws  = ws + HE;
    float* va_ws = ws + 2 * HE;
    float* vb_ws = ws + 3 * HE;
    unsigned short* k2bf = (unsigned short*)(ws + 4 * HE);          // HE ushorts
    unsigned short* z_bf = (unsigned short*)(ws + 4 * HE) + HE;     // HE ushorts

    proj_kernel<<<dim3(40, 8), 256, 0, stream>>>(x, W_kkq, b_kkq, Wv_a, Wv_b,
                                                 k1_ws, k2bf, q_ws, va_ws, vb_ws);
    tri_kernel<<<dim3(32, H_, B_), 256, 0, stream>>>(k1_ws, k2bf, q_ws,
                                                     va_ws, vb_ws, b_v, z_bf);
    out_kernel<<<dim3(8, 16), 256, 0, stream>>>(z_bf, W_out, b_out, out);
}